// Round 7
// baseline (2022.582 us; speedup 1.0000x reference)
//
#include <hip/hip_runtime.h>

typedef __bf16 bf16x8 __attribute__((ext_vector_type(8)));
typedef __bf16 bf16x4 __attribute__((ext_vector_type(4)));
typedef float  f32x4  __attribute__((ext_vector_type(4)));

#define NPIX  3136      // 56*56 = 49*64 = 98*32 (no tails)
#define WIMG  56
#define CCH   128
#define NH    4
#define HD    32
#define NSPLIT 8        // key-splits per (head, 32q) tile
// 32^-0.5 * log2(e): q pre-scaled so softmax uses exp2 directly
#define QSCALE 0.2550565470841439f

#if __has_builtin(__builtin_amdgcn_exp2f)
#define FEXP2(x) __builtin_amdgcn_exp2f(x)
#else
#define FEXP2(x) __expf((x) * 0.6931471805599453f)
#endif

// MFMA 16x16x32 fragment maps (HW-verified R1-R6):
//   A[m=lane&15][k=(lane>>4)*8+j]   B[k=(lane>>4)*8+j][n=lane&15]
//   D: col(n)=lane&15, row(m)=(lane>>4)*4+reg
// Key permutation inside each 64-key block: storage slot s holds key
// 16*(s&3)+(s>>2), so QK chunk-c output packs to slot 4*col+c (one b64 LDS
// write per lane); vP is pre-permuted to match (free: permutes a sum index).

// ---------------------------------------------------------------------------
// K1: qkv = qkv_w @ x + qkv_b, bf16 MFMA (M=384, K=128, N=6272).  (R6 kernel)
// grid (49, 3, 2), block 256. Slab = 128 outputs (q | k | v).
// ---------------------------------------------------------------------------
__global__ __launch_bounds__(256) void k_qkv(
    const float* __restrict__ x, const float* __restrict__ qkv_w,
    const float* __restrict__ qkv_b,
    __bf16* __restrict__ qT, __bf16* __restrict__ kT,
    __bf16* __restrict__ vT, __bf16* __restrict__ vP)
{
    __shared__ __bf16 xl[64][136];                 // [px][c], row stride 272B
    const int tid = threadIdx.x;
    const int w = tid >> 6, lane = tid & 63;
    const int col = lane & 15, g = lane >> 4;
    const int px0 = blockIdx.x * 64;
    const int slab = blockIdx.y;                   // 0 q, 1 k, 2 v
    const int b = blockIdx.z;
    const int obase = slab * 128 + w * 32;

    {   // stage x tile (coalesced dword loads, packed b64 LDS writes)
        const int px = tid & 63, cq = tid >> 6;
        const float* xp = x + (size_t)b * CCH * NPIX + px0 + px;
        #pragma unroll
        for (int i = 0; i < 8; ++i) {
            const int c0 = cq * 4 + i * 16;
            const float v0 = xp[(size_t)(c0 + 0) * NPIX];
            const float v1 = xp[(size_t)(c0 + 1) * NPIX];
            const float v2 = xp[(size_t)(c0 + 2) * NPIX];
            const float v3 = xp[(size_t)(c0 + 3) * NPIX];
            bf16x4 bv = {(__bf16)v0, (__bf16)v1, (__bf16)v2, (__bf16)v3};
            *(bf16x4*)&xl[px][c0] = bv;
        }
    }
    __syncthreads();

    f32x4 acc[2][4];                               // [out tile][px tile]
    #pragma unroll
    for (int ot = 0; ot < 2; ++ot)
        #pragma unroll
        for (int a = 0; a < 4; ++a) acc[ot][a] = (f32x4){0.f, 0.f, 0.f, 0.f};

    #pragma unroll
    for (int ks = 0; ks < 4; ++ks) {
        const int c0 = ks * 32 + g * 8;
        #pragma unroll
        for (int ot = 0; ot < 2; ++ot) {
            const float* wrow = qkv_w + (size_t)(obase + ot * 16 + col) * CCH + c0;
            const float4 wA = *(const float4*)(wrow);
            const float4 wB = *(const float4*)(wrow + 4);
            bf16x8 af = {(__bf16)wA.x, (__bf16)wA.y, (__bf16)wA.z, (__bf16)wA.w,
                         (__bf16)wB.x, (__bf16)wB.y, (__bf16)wB.z, (__bf16)wB.w};
            #pragma unroll
            for (int a = 0; a < 4; ++a) {
                const bf16x8 bf_ = *(const bf16x8*)&xl[16 * a + col][c0];  // one b128
                acc[ot][a] = __builtin_amdgcn_mfma_f32_16x16x32_bf16(af, bf_, acc[ot][a], 0, 0, 0);
            }
        }
    }

    #pragma unroll
    for (int ot = 0; ot < 2; ++ot) {
        const int orow = obase + ot * 16 + g * 4;      // global output row
        const f32x4 bias4 = *(const f32x4*)(qkv_b + orow);
        if (slab == 0) {                               // ---- q (scaled) ----
            const int o = orow, h = o >> 5, d0 = o & 31;
            __bf16* dst = qT + ((size_t)(b * NH + h) * NPIX) * HD + d0;
            #pragma unroll
            for (int a = 0; a < 4; ++a) {
                const int px = px0 + 16 * a + col;
                bf16x4 v;
                #pragma unroll
                for (int r = 0; r < 4; ++r) v[r] = (__bf16)((acc[ot][a][r] + bias4[r]) * QSCALE);
                *(bf16x4*)(dst + (size_t)px * HD) = v;
            }
        } else if (slab == 1) {                        // ---- k ----
            const int o = orow - 128, h = o >> 5, d0 = o & 31;
            __bf16* dst = kT + ((size_t)(b * NH + h) * NPIX) * HD + d0;
            #pragma unroll
            for (int a = 0; a < 4; ++a) {
                const int px = px0 + 16 * a + col;
                bf16x4 v;
                #pragma unroll
                for (int r = 0; r < 4; ++r) v[r] = (__bf16)(acc[ot][a][r] + bias4[r]);
                *(bf16x4*)(dst + (size_t)px * HD) = v;
            }
        } else {                                       // ---- v: vT + permuted vP ----
            const int c = orow - 256;
            #pragma unroll
            for (int a = 0; a < 4; ++a) {
                const int px = px0 + 16 * a + col;
                bf16x4 v;
                #pragma unroll
                for (int r = 0; r < 4; ++r) v[r] = (__bf16)(acc[ot][a][r] + bias4[r]);
                *(bf16x4*)(vT + ((size_t)(b * NPIX + px)) * CCH + c) = v;
                const int sp = px0 + 4 * col + a;      // permuted slot of key px
                #pragma unroll
                for (int r = 0; r < 4; ++r)
                    vP[((size_t)(b * CCH + c + r)) * NPIX + sp] = v[r];
            }
        }
    }
}

// ---------------------------------------------------------------------------
// K2: attention partials, SOFTWARE-PIPELINED so every consumer is >=1 loop
// body (~600 cyc) from its producer:
//   iter i: [prefetch K(i+1)] [read P(i-1); PV(i-1); L(i-1)] [prefetch V(i+1)]
//           [QK(i); exp(i); write P(i)]
// P double-buffered per wave in LDS; K/V depth-1 register prefetch.
// 2 waves/WG (128 thr, no barriers). grid (49, 8, 8). Row-sums via MFMA-ones.
// Outputs UNNORMALIZED: pO bf16 [t][s][q 32][d 32], pl f32 [t][s][q 32].
// ---------------------------------------------------------------------------
__global__ __launch_bounds__(128) void k_attn(
    const __bf16* __restrict__ qT, const __bf16* __restrict__ kT,
    const __bf16* __restrict__ vP,
    __bf16* __restrict__ pO, float* __restrict__ pl)
{
    __shared__ __bf16 P[2][2][32][72];     // [wave][buf][q][slot]
    const int tid = threadIdx.x;
    const int w = tid >> 6, lane = tid & 63;
    const int col = lane & 15, g = lane >> 4;
    const int qt = blockIdx.x * 2 + w;
    const int bh = blockIdx.y, sp = blockIdx.z;
    const int b = bh >> 2, h = bh & 3;
    const int qbase = qt * 32;
    const size_t headoff = (size_t)bh * NPIX * HD;
    const int c0h = h * HD;

    const bf16x8 aqA = *(const bf16x8*)(qT + headoff + (size_t)(qbase + col) * HD + g * 8);
    const bf16x8 aqB = *(const bf16x8*)(qT + headoff + (size_t)(qbase + 16 + col) * HD + g * 8);

    const __bf16 one = (__bf16)1.0f;
    const bf16x8 ones = {one, one, one, one, one, one, one, one};

    f32x4 O[2][2], Lacc[2];
    #pragma unroll
    for (int i = 0; i < 2; ++i) {
        Lacc[i] = (f32x4){0.f, 0.f, 0.f, 0.f};
        #pragma unroll
        for (int j = 0; j < 2; ++j) O[i][j] = (f32x4){0.f, 0.f, 0.f, 0.f};
    }

    const __bf16* kTh   = kT + headoff;
    const __bf16* vrow0 = vP + (size_t)(b * CCH + c0h + col)      * NPIX;
    const __bf16* vrow1 = vP + (size_t)(b * CCH + c0h + 16 + col) * NPIX;

    const int cs = (49 * sp) >> 3, ce = (49 * (sp + 1)) >> 3;   // 6 or 7 chunks
    const int nch = ce - cs;

    bf16x8 K[2][4], V[2][4];

#define LOADK(DST, CHUNK) do { const int _k0 = (CHUNK) * 64;                               \
        _Pragma("unroll")                                                                  \
        for (int _c = 0; _c < 4; ++_c)                                                     \
            DST[_c] = *(const bf16x8*)(kTh + (size_t)(_k0 + 16 * _c + col) * HD + g * 8);  \
        } while (0)
#define LOADV(DST, CHUNK) do { const int _k0 = (CHUNK) * 64;                               \
        DST[0] = *(const bf16x8*)(vrow0 + _k0      + g * 8);                               \
        DST[1] = *(const bf16x8*)(vrow0 + _k0 + 32 + g * 8);                               \
        DST[2] = *(const bf16x8*)(vrow1 + _k0      + g * 8);                               \
        DST[3] = *(const bf16x8*)(vrow1 + _k0 + 32 + g * 8); } while (0)

    // QK + exp + P-write for relative chunk i (P buf i&1), using K regs kk
#define QKEXP(I, KK) do {                                                                  \
        const f32x4 _z = {0.f, 0.f, 0.f, 0.f};                                             \
        _Pragma("unroll")                                                                  \
        for (int _qh = 0; _qh < 2; ++_qh) {                                                \
            const bf16x8 _aq = _qh ? aqB : aqA;                                            \
            f32x4 _s0 = __builtin_amdgcn_mfma_f32_16x16x32_bf16(_aq, KK[0], _z, 0, 0, 0);  \
            f32x4 _s1 = __builtin_amdgcn_mfma_f32_16x16x32_bf16(_aq, KK[1], _z, 0, 0, 0);  \
            f32x4 _s2 = __builtin_amdgcn_mfma_f32_16x16x32_bf16(_aq, KK[2], _z, 0, 0, 0);  \
            f32x4 _s3 = __builtin_amdgcn_mfma_f32_16x16x32_bf16(_aq, KK[3], _z, 0, 0, 0);  \
            _Pragma("unroll")                                                              \
            for (int _r = 0; _r < 4; ++_r) {                                               \
                bf16x4 _pv = {(__bf16)FEXP2(_s0[_r]), (__bf16)FEXP2(_s1[_r]),              \
                              (__bf16)FEXP2(_s2[_r]), (__bf16)FEXP2(_s3[_r])};             \
                *(bf16x4*)&P[w][(I) & 1][_qh * 16 + g * 4 + _r][4 * col] = _pv;            \
            }                                                                              \
        } } while (0)

    // P-read + PV + L for relative chunk i, using V regs vv
#define PVACC(I, VV) do {                                                                  \
        _Pragma("unroll")                                                                  \
        for (int _qh = 0; _qh < 2; ++_qh) {                                                \
            const bf16x8 _ap0 = *(const bf16x8*)&P[w][(I) & 1][_qh * 16 + col][g * 8];     \
            const bf16x8 _ap1 = *(const bf16x8*)&P[w][(I) & 1][_qh * 16 + col][32 + g * 8];\
            O[_qh][0] = __builtin_amdgcn_mfma_f32_16x16x32_bf16(_ap0, VV[0], O[_qh][0], 0, 0, 0); \
            O[_qh][0] = __builtin_amdgcn_mfma_f32_16x16x32_bf16(_ap1, VV[1], O[_qh][0], 0, 0, 0); \
            O[_qh][1] = __builtin_amdgcn_mfma_f32_16x16x32_bf16(_ap0, VV[2], O[_qh][1], 0, 0, 0); \
            O[_qh][1] = __builtin_amdgcn_mfma_f32_16x16x32_bf16(_ap1, VV[3], O[_qh][1], 0, 0, 0); \
            Lacc[_qh] = __builtin_amdgcn_mfma_f32_16x16x32_bf16(_ap0, ones, Lacc[_qh], 0, 0, 0);  \
            Lacc[_qh] = __builtin_amdgcn_mfma_f32_16x16x32_bf16(_ap1, ones, Lacc[_qh], 0, 0, 0);  \
        } } while (0)

    // ---- prologue: fill depth-1 prefetch, run chunk 0's QK/exp ----
    LOADK(K[0], cs);  LOADV(V[0], cs);
    LOADK(K[1], cs + 1);                       // nch >= 6 always
    QKEXP(0, K[0]);
    LOADV(V[1], cs + 1);

    // ---- steady state ----
    for (int i = 1; i < nch; ++i) {
        const int cur = i & 1, nxt = cur ^ 1;  // nxt == (i+1)&1 == (i-1)&1
        if (i + 1 < nch) LOADK(K[nxt], cs + i + 1);
        PVACC(i - 1, V[nxt]);                  // consumes V(i-1)  [slot nxt]
        if (i + 1 < nch) LOADV(V[nxt], cs + i + 1);   // refill slot with V(i+1)
        QKEXP(i, K[cur]);
    }
    // ---- epilogue ----
    PVACC(nch - 1, V[(nch - 1) & 1]);
#undef LOADK
#undef LOADV
#undef QKEXP
#undef PVACC

    // store partials: pO[t][s][q][d] (coalesced for the reducer), pl f32
    const int t = bh * 98 + qt;
    __bf16* po = pO + ((size_t)t * NSPLIT + sp) * 1024;
    #pragma unroll
    for (int qh = 0; qh < 2; ++qh)
        #pragma unroll
        for (int dh = 0; dh < 2; ++dh)
            #pragma unroll
            for (int r = 0; r < 4; ++r)
                po[(qh * 16 + g * 4 + r) * 32 + dh * 16 + col] = (__bf16)O[qh][dh][r];
    if (col == 0) {
        float* plp = pl + ((size_t)t * NSPLIT + sp) * 32;
        *(f32x4*)(plp + g * 4)      = Lacc[0];
        *(f32x4*)(plp + 16 + g * 4) = Lacc[1];
    }
}

// ---------------------------------------------------------------------------
// K3: reduce 8 split partials + normalize + LePE + bias -> attnT [b][px][c].
// grid (98, 8) = 784 blocks, block 256: thread = (q, 4-channel group) for ONE
// head. pO reads are contiguous 16B per lane-group (R6 layout).
// ---------------------------------------------------------------------------
__global__ __launch_bounds__(256) void k_reduce(
    const __bf16* __restrict__ pO, const float* __restrict__ pl,
    const __bf16* __restrict__ vT,
    const float* __restrict__ lepe_w, const float* __restrict__ lepe_b,
    __bf16* __restrict__ attnT)
{
    __shared__ float wl[32][25];
    __shared__ float bl[32];
    const int tid = threadIdx.x;
    const int qt = blockIdx.x, bh = blockIdx.y;
    const int b = bh >> 2, h = bh & 3;
    const int c0h = h * HD;

    for (int i = tid; i < 800; i += 256) ((float*)wl)[i] = lepe_w[c0h * 25 + i];
    if (tid < 32) bl[tid] = lepe_b[c0h + tid];
    __syncthreads();

    const int q = tid >> 3;                    // 0..31
    const int cq = (tid & 7) * 4;              // 0,4,...,28
    const size_t t = (size_t)bh * 98 + qt;

    float lt = 0.f;
    float o[4] = {0.f, 0.f, 0.f, 0.f};
    #pragma unroll
    for (int s = 0; s < NSPLIT; ++s) {
        lt += pl[(t * NSPLIT + s) * 32 + q];
        const bf16x4 pv = *(const bf16x4*)(pO + (t * NSPLIT + s) * 1024 + q * 32 + cq);
        #pragma unroll
        for (int i = 0; i < 4; ++i) o[i] += (float)pv[i];
    }
    const float linv = 1.0f / lt;
    #pragma unroll
    for (int i = 0; i < 4; ++i) o[i] = o[i] * linv + bl[cq + i];

    const int px = qt * 32 + q;
    const int py = px / WIMG, pxx = px % WIMG;
    const __bf16* vtb = vT + ((size_t)b * NPIX) * CCH + c0h + cq;
    #pragma unroll
    for (int dy = 0; dy < 5; ++dy) {
        const int yy = py + dy - 2;
        if (yy < 0 || yy >= WIMG) continue;
        #pragma unroll
        for (int dx = 0; dx < 5; ++dx) {
            const int xx = pxx + dx - 2;
            if (xx < 0 || xx >= WIMG) continue;
            const bf16x4 vv = *(const bf16x4*)(vtb + (size_t)(yy * WIMG + xx) * CCH);
            const int tap = dy * 5 + dx;
            #pragma unroll
            for (int i = 0; i < 4; ++i) o[i] += (float)vv[i] * wl[cq + i][tap];
        }
    }
    bf16x4 ov = {(__bf16)o[0], (__bf16)o[1], (__bf16)o[2], (__bf16)o[3]};
    *(bf16x4*)(attnT + ((size_t)(b * NPIX + px)) * CCH + c0h + cq) = ov;
}

// ---------------------------------------------------------------------------
// K4: out = proj_w @ (attn+lepe) + proj_b, bf16 MFMA, zero LDS.
// grid (98, 4, 2) = 784 blocks, block 256; wave tile = 16 outputs x 16 px.
// ---------------------------------------------------------------------------
__global__ __launch_bounds__(256) void k_proj(
    const __bf16* __restrict__ attnT, const float* __restrict__ proj_w,
    const float* __restrict__ proj_b, float* __restrict__ out)
{
    const int tid = threadIdx.x;
    const int w = tid >> 6, lane = tid & 63;
    const int col = lane & 15, g = lane >> 4;
    const int px0 = blockIdx.x * 32 + (w >> 1) * 16;
    const int obase = blockIdx.y * 32 + (w & 1) * 16;
    const int b = blockIdx.z;

    const float* wrow = proj_w + (size_t)(obase + col) * CCH;
    const __bf16* abase = attnT + (size_t)(b * NPIX + px0) * CCH;

    f32x4 acc = {0.f, 0.f, 0.f, 0.f};
    #pragma unroll
    for (int ks = 0; ks < 4; ++ks) {
        const int c0 = ks * 32 + g * 8;
        const float4 wA = *(const float4*)(wrow + c0);
        const float4 wB = *(const float4*)(wrow + c0 + 4);
        bf16x8 af = {(__bf16)wA.x, (__bf16)wA.y, (__bf16)wA.z, (__bf16)wA.w,
                     (__bf16)wB.x, (__bf16)wB.y, (__bf16)wB.z, (__bf16)wB.w};
        const bf16x8 bf_ = *(const bf16x8*)(abase + (size_t)col * CCH + c0);
        acc = __builtin_amdgcn_mfma_f32_16x16x32_bf16(af, bf_, acc, 0, 0, 0);
    }

    const f32x4 pb = *(const f32x4*)(proj_b + obase + g * 4);
    #pragma unroll
    for (int r = 0; r < 4; ++r)
        out[(size_t)(b * CCH + obase + g * 4 + r) * NPIX + px0 + col] = acc[r] + pb[r];
}

// ---------------------------------------------------------------------------
extern "C" void kernel_launch(void* const* d_in, const int* in_sizes, int n_in,
                              void* d_out, int out_size, void* d_ws, size_t ws_size,
                              hipStream_t stream)
{
    const float* x      = (const float*)d_in[0];
    const float* qkv_w  = (const float*)d_in[1];
    const float* qkv_b  = (const float*)d_in[2];
    const float* lepe_w = (const float*)d_in[3];
    const float* lepe_b = (const float*)d_in[4];
    const float* proj_w = (const float*)d_in[5];
    const float* proj_b = (const float*)d_in[6];
    float* out = (float*)d_out;

    char* p = (char*)d_ws;                                   // ~21.7 MB total
    __bf16* qT    = (__bf16*)p;  p += (size_t)2 * NH * NPIX * HD * 2;   // 1.6 MB
    __bf16* kT    = (__bf16*)p;  p += (size_t)2 * NH * NPIX * HD * 2;   // 1.6 MB
    __bf16* vT    = (__bf16*)p;  p += (size_t)2 * NPIX * CCH * 2;       // 1.6 MB
    __bf16* vP    = (__bf16*)p;  p += (size_t)2 * CCH * NPIX * 2;       // 1.6 MB
    __bf16* attnT = (__bf16*)p;  p += (size_t)2 * NPIX * CCH * 2;       // 1.6 MB
    __bf16* pO    = (__bf16*)p;  p += (size_t)784 * NSPLIT * 1024 * 2;  // 12.8 MB
    float*  pl    = (float*)p;                                          // 0.8 MB

    k_qkv   <<<dim3(49, 3, 2),      dim3(256), 0, stream>>>(x, qkv_w, qkv_b, qT, kT, vT, vP);
    k_attn  <<<dim3(49, 8, NSPLIT), dim3(128), 0, stream>>>(qT, kT, vP, pO, pl);
    k_reduce<<<dim3(98, 8),         dim3(256), 0, stream>>>(pO, pl, vT, lepe_w, lepe_b, attnT);
    k_proj  <<<dim3(98, 4, 2),      dim3(256), 0, stream>>>(attnT, proj_w, proj_b, out);
}

// Round 8
// 133.200 us; speedup vs baseline: 15.1846x; 15.1846x over previous
//
#include <hip/hip_runtime.h>

typedef __bf16 bf16x8 __attribute__((ext_vector_type(8)));
typedef __bf16 bf16x4 __attribute__((ext_vector_type(4)));
typedef float  f32x4  __attribute__((ext_vector_type(4)));

#define NPIX  3136      // 56*56 = 49*64 (no tails)
#define WIMG  56
#define CCH   128
#define NH    4
#define HD    32
#define NSPLIT 4        // key-splits per (head, 32q) tile
// 32^-0.5 * log2(e): q pre-scaled so softmax uses exp2 directly
#define QSCALE 0.2550565470841439f

#if __has_builtin(__builtin_amdgcn_exp2f)
#define FEXP2(x) __builtin_amdgcn_exp2f(x)
#else
#define FEXP2(x) __expf((x) * 0.6931471805599453f)
#endif

// MFMA 16x16x32 maps (HW-verified R1-R6):
//   A[m=lane&15][k=(lane>>4)*8+j]   B[k=(lane>>4)*8+j][n=lane&15]
//   D: col(n)=lane&15, row(m)=(lane>>4)*4+reg
// NOTE: A and B have the SAME lane->data map, so one register fragment can
// serve as either operand.
//
// R8 key-slot permutation (transpose-free attention): compute S^T = A*B with
// A=K-frag, B=Q-frag. Output: lane&15=query, reg (c,r) = key slot s=16c+4g+r.
// Map regs (c,r) -> PV B-frag (p=c>>1, j=4*(c&1)+r), i.e. slot s holds
// physical key pi(s) = 32*(c>>1) | 8*g | 4*(c&1) | r. Storing kT rows and vP
// columns in pi-order makes exp(S^T) registers DIRECTLY the PV B-fragments:
// no LDS round-trip, no cross-lane ops. pi^-1(kappa) =
// 16*(2*bit5(kappa)|bit2(kappa)) + 4*bits34(kappa) + bits01(kappa).

__device__ __forceinline__ int perm_inv(int k) {
    return (((k >> 5) & 1) * 2 + ((k >> 2) & 1)) * 16 + (((k >> 3) & 3) * 4) + (k & 3);
}

// ---------------------------------------------------------------------------
// K1: qkv = qkv_w @ x + qkv_b, bf16 MFMA (M=384, K=128, N=6272).
// grid (49, 3, 2), block 256. Slab = 128 outputs (q | k | v).
// kT rows and vP columns are written in pi-permuted slot order.
// ---------------------------------------------------------------------------
__global__ __launch_bounds__(256) void k_qkv(
    const float* __restrict__ x, const float* __restrict__ qkv_w,
    const float* __restrict__ qkv_b,
    __bf16* __restrict__ qT, __bf16* __restrict__ kT,
    __bf16* __restrict__ vT, __bf16* __restrict__ vP)
{
    __shared__ __bf16 xl[64][136];                 // [px][c], row stride 272B
    const int tid = threadIdx.x;
    const int w = tid >> 6, lane = tid & 63;
    const int col = lane & 15, g = lane >> 4;
    const int px0 = blockIdx.x * 64;
    const int slab = blockIdx.y;                   // 0 q, 1 k, 2 v
    const int b = blockIdx.z;
    const int obase = slab * 128 + w * 32;

    {   // stage x tile (coalesced dword loads, packed b64 LDS writes)
        const int px = tid & 63, cq = tid >> 6;
        const float* xp = x + (size_t)b * CCH * NPIX + px0 + px;
        #pragma unroll
        for (int i = 0; i < 8; ++i) {
            const int c0 = cq * 4 + i * 16;
            const float v0 = xp[(size_t)(c0 + 0) * NPIX];
            const float v1 = xp[(size_t)(c0 + 1) * NPIX];
            const float v2 = xp[(size_t)(c0 + 2) * NPIX];
            const float v3 = xp[(size_t)(c0 + 3) * NPIX];
            bf16x4 bv = {(__bf16)v0, (__bf16)v1, (__bf16)v2, (__bf16)v3};
            *(bf16x4*)&xl[px][c0] = bv;
        }
    }
    __syncthreads();

    f32x4 acc[2][4];                               // [out tile][px tile]
    #pragma unroll
    for (int ot = 0; ot < 2; ++ot)
        #pragma unroll
        for (int a = 0; a < 4; ++a) acc[ot][a] = (f32x4){0.f, 0.f, 0.f, 0.f};

    #pragma unroll
    for (int ks = 0; ks < 4; ++ks) {
        const int c0 = ks * 32 + g * 8;
        #pragma unroll
        for (int ot = 0; ot < 2; ++ot) {
            const float* wrow = qkv_w + (size_t)(obase + ot * 16 + col) * CCH + c0;
            const float4 wA = *(const float4*)(wrow);
            const float4 wB = *(const float4*)(wrow + 4);
            bf16x8 af = {(__bf16)wA.x, (__bf16)wA.y, (__bf16)wA.z, (__bf16)wA.w,
                         (__bf16)wB.x, (__bf16)wB.y, (__bf16)wB.z, (__bf16)wB.w};
            #pragma unroll
            for (int a = 0; a < 4; ++a) {
                const bf16x8 bf_ = *(const bf16x8*)&xl[16 * a + col][c0];  // one b128
                acc[ot][a] = __builtin_amdgcn_mfma_f32_16x16x32_bf16(af, bf_, acc[ot][a], 0, 0, 0);
            }
        }
    }

    #pragma unroll
    for (int ot = 0; ot < 2; ++ot) {
        const int orow = obase + ot * 16 + g * 4;      // global output row
        const f32x4 bias4 = *(const f32x4*)(qkv_b + orow);
        if (slab == 0) {                               // ---- q (scaled) ----
            const int o = orow, h = o >> 5, d0 = o & 31;
            __bf16* dst = qT + ((size_t)(b * NH + h) * NPIX) * HD + d0;
            #pragma unroll
            for (int a = 0; a < 4; ++a) {
                const int px = px0 + 16 * a + col;
                bf16x4 v;
                #pragma unroll
                for (int r = 0; r < 4; ++r) v[r] = (__bf16)((acc[ot][a][r] + bias4[r]) * QSCALE);
                *(bf16x4*)(dst + (size_t)px * HD) = v;
            }
        } else if (slab == 1) {                        // ---- k (pi-permuted rows) ----
            const int o = orow - 128, h = o >> 5, d0 = o & 31;
            __bf16* dst = kT + ((size_t)(b * NH + h) * NPIX) * HD + d0;
            #pragma unroll
            for (int a = 0; a < 4; ++a) {
                const int s = perm_inv(16 * a + col);  // slot for key kappa
                bf16x4 v;
                #pragma unroll
                for (int r = 0; r < 4; ++r) v[r] = (__bf16)(acc[ot][a][r] + bias4[r]);
                *(bf16x4*)(dst + (size_t)(px0 + s) * HD) = v;
            }
        } else {                                       // ---- v: vT + pi-permuted vP ----
            const int c = orow - 256;
            #pragma unroll
            for (int a = 0; a < 4; ++a) {
                const int px = px0 + 16 * a + col;
                const int s = perm_inv(16 * a + col);
                bf16x4 v;
                #pragma unroll
                for (int r = 0; r < 4; ++r) v[r] = (__bf16)(acc[ot][a][r] + bias4[r]);
                *(bf16x4*)(vT + ((size_t)(b * NPIX + px)) * CCH + c) = v;
                #pragma unroll
                for (int r = 0; r < 4; ++r)
                    vP[((size_t)(b * CCH + c + r)) * NPIX + px0 + s] = v[r];
            }
        }
    }
}

// ---------------------------------------------------------------------------
// K2: attention partials, TRANSPOSE-FREE (zero LDS, zero cross-lane).
// Per chunk: load K A-frags -> S^T MFMAs -> exp+pack (registers ARE the PV
// B-frags thanks to pi) -> PV MFMAs (A = V^T frags) + L via MFMA-vs-ones.
// 4 independent waves/WG (no barriers); wave = (qtile, head, split) task.
// grid (49, 8, 2): qt = 2*bx + (w>>1), sp = 2*bz + (w&1); 12-13 chunks/wave.
// Static ping-pong on K (named kA/kB regs -- NO runtime-indexed arrays, R7!).
// Outputs UNNORMALIZED: pO bf16 [t][s][q 32][d 32], pl f32 [t][s][q 32].
// ---------------------------------------------------------------------------
__global__ __launch_bounds__(256) void k_attn(
    const __bf16* __restrict__ qT, const __bf16* __restrict__ kT,
    const __bf16* __restrict__ vP,
    __bf16* __restrict__ pO, float* __restrict__ pl)
{
    const int tid = threadIdx.x;
    const int w = tid >> 6, lane = tid & 63;
    const int col = lane & 15, g = lane >> 4;
    const int qt = blockIdx.x * 2 + (w >> 1);
    const int bh = blockIdx.y;
    const int sp = blockIdx.z * 2 + (w & 1);
    const int b = bh >> 2, h = bh & 3;
    const int qbase = qt * 32;
    const size_t headoff = (size_t)bh * NPIX * HD;
    const int c0h = h * HD;

    // Q fragments (serve as MFMA B operands; same lane map as A)
    const bf16x8 aqA = *(const bf16x8*)(qT + headoff + (size_t)(qbase + col) * HD + g * 8);
    const bf16x8 aqB = *(const bf16x8*)(qT + headoff + (size_t)(qbase + 16 + col) * HD + g * 8);

    const __bf16 one = (__bf16)1.0f;
    const bf16x8 ones = {one, one, one, one, one, one, one, one};

    f32x4 O[2][2], Lacc[2];                   // O[qh][dh], D: col=q, row=d_local
    #pragma unroll
    for (int i = 0; i < 2; ++i) {
        Lacc[i] = (f32x4){0.f, 0.f, 0.f, 0.f};
        #pragma unroll
        for (int j = 0; j < 2; ++j) O[i][j] = (f32x4){0.f, 0.f, 0.f, 0.f};
    }

    const __bf16* kTh   = kT + headoff;
    const __bf16* vrow0 = vP + (size_t)(b * CCH + c0h + col)      * NPIX;  // d = col
    const __bf16* vrow1 = vP + (size_t)(b * CCH + c0h + 16 + col) * NPIX;  // d = col+16

    const int cs = (49 * sp) >> 2, ce = (49 * (sp + 1)) >> 2;   // 12 or 13 chunks
    const int nch = ce - cs;

#define LOADK(DK, CHUNK) do { const int _k0 = (CHUNK) * 64;                               \
        _Pragma("unroll")                                                                  \
        for (int _c = 0; _c < 4; ++_c)                                                     \
            DK[_c] = *(const bf16x8*)(kTh + (size_t)(_k0 + 16 * _c + col) * HD + g * 8);   \
        } while (0)

    auto compute = [&](const bf16x8* bk, int chunk) {
        const int k0 = chunk * 64;
        // V^T A-frags: lane (d_local=col, g), reg j -> slot 32p+8g+j (contiguous)
        const bf16x8 vv00 = *(const bf16x8*)(vrow0 + k0      + g * 8);  // dh0, p0
        const bf16x8 vv01 = *(const bf16x8*)(vrow0 + k0 + 32 + g * 8);  // dh0, p1
        const bf16x8 vv10 = *(const bf16x8*)(vrow1 + k0      + g * 8);  // dh1, p0
        const bf16x8 vv11 = *(const bf16x8*)(vrow1 + k0 + 32 + g * 8);  // dh1, p1
        const f32x4 z = {0.f, 0.f, 0.f, 0.f};
        #pragma unroll
        for (int qh = 0; qh < 2; ++qh) {
            const bf16x8 aq = qh ? aqB : aqA;
            // S^T: A = K-frag (m=slot), B = Q-frag (n=query)
            f32x4 s0 = __builtin_amdgcn_mfma_f32_16x16x32_bf16(bk[0], aq, z, 0, 0, 0);
            f32x4 s1 = __builtin_amdgcn_mfma_f32_16x16x32_bf16(bk[1], aq, z, 0, 0, 0);
            f32x4 s2 = __builtin_amdgcn_mfma_f32_16x16x32_bf16(bk[2], aq, z, 0, 0, 0);
            f32x4 s3 = __builtin_amdgcn_mfma_f32_16x16x32_bf16(bk[3], aq, z, 0, 0, 0);
            // exp -> registers ARE PV B-frags: P0 = (c0,c1), P1 = (c2,c3)
            bf16x8 P0 = {(__bf16)FEXP2(s0[0]), (__bf16)FEXP2(s0[1]),
                         (__bf16)FEXP2(s0[2]), (__bf16)FEXP2(s0[3]),
                         (__bf16)FEXP2(s1[0]), (__bf16)FEXP2(s1[1]),
                         (__bf16)FEXP2(s1[2]), (__bf16)FEXP2(s1[3])};
            bf16x8 P1 = {(__bf16)FEXP2(s2[0]), (__bf16)FEXP2(s2[1]),
                         (__bf16)FEXP2(s2[2]), (__bf16)FEXP2(s2[3]),
                         (__bf16)FEXP2(s3[0]), (__bf16)FEXP2(s3[1]),
                         (__bf16)FEXP2(s3[2]), (__bf16)FEXP2(s3[3])};
            O[qh][0] = __builtin_amdgcn_mfma_f32_16x16x32_bf16(vv00, P0, O[qh][0], 0, 0, 0);
            O[qh][0] = __builtin_amdgcn_mfma_f32_16x16x32_bf16(vv01, P1, O[qh][0], 0, 0, 0);
            O[qh][1] = __builtin_amdgcn_mfma_f32_16x16x32_bf16(vv10, P0, O[qh][1], 0, 0, 0);
            O[qh][1] = __builtin_amdgcn_mfma_f32_16x16x32_bf16(vv11, P1, O[qh][1], 0, 0, 0);
            Lacc[qh] = __builtin_amdgcn_mfma_f32_16x16x32_bf16(ones, P0, Lacc[qh], 0, 0, 0);
            Lacc[qh] = __builtin_amdgcn_mfma_f32_16x16x32_bf16(ones, P1, Lacc[qh], 0, 0, 0);
        }
    };

    bf16x8 kA[4], kB[4];
    LOADK(kA, cs);
    int cc = cs;
    while (cc + 2 <= ce) {                      // static ping-pong (kA/kB named)
        LOADK(kB, cc + 1);
        compute(kA, cc);
        LOADK(kA, (cc + 2 < ce) ? cc + 2 : cs);   // dummy reload ok
        compute(kB, cc + 1);
        cc += 2;
    }
    if (cc < ce) compute(kA, cc);               // odd tail (13-chunk splits)
#undef LOADK

    // store partials: O D-layout col=q, row=d_local=4g+r (dh gives +16)
    const int t = bh * 98 + qt;
    __bf16* po = pO + ((size_t)t * NSPLIT + sp) * 1024;
    #pragma unroll
    for (int qh = 0; qh < 2; ++qh)
        #pragma unroll
        for (int dh = 0; dh < 2; ++dh) {
            bf16x4 v = {(__bf16)O[qh][dh][0], (__bf16)O[qh][dh][1],
                        (__bf16)O[qh][dh][2], (__bf16)O[qh][dh][3]};
            *(bf16x4*)(po + (qh * 16 + col) * 32 + dh * 16 + g * 4) = v;
        }
    if (g == 0) {                               // L: all rows equal L[q]
        float* plp = pl + ((size_t)t * NSPLIT + sp) * 32;
        plp[col]      = Lacc[0][0];
        plp[col + 16] = Lacc[1][0];
    }
}

// ---------------------------------------------------------------------------
// K3: reduce 4 split partials + normalize + LePE + bias -> attnT [b][px][c].
// grid (98, 8) = 784 blocks, block 256: thread = (q, 4-channel group), 1 head.
// ---------------------------------------------------------------------------
__global__ __launch_bounds__(256) void k_reduce(
    const __bf16* __restrict__ pO, const float* __restrict__ pl,
    const __bf16* __restrict__ vT,
    const float* __restrict__ lepe_w, const float* __restrict__ lepe_b,
    __bf16* __restrict__ attnT)
{
    __shared__ float wl[32][25];
    __shared__ float bl[32];
    const int tid = threadIdx.x;
    const int qt = blockIdx.x, bh = blockIdx.y;
    const int b = bh >> 2, h = bh & 3;
    const int c0h = h * HD;

    for (int i = tid; i < 800; i += 256) ((float*)wl)[i] = lepe_w[c0h * 25 + i];
    if (tid < 32) bl[tid] = lepe_b[c0h + tid];
    __syncthreads();

    const int q = tid >> 3;                    // 0..31
    const int cq = (tid & 7) * 4;              // 0,4,...,28
    const size_t t = (size_t)bh * 98 + qt;

    float lt = 0.f;
    float o[4] = {0.f, 0.f, 0.f, 0.f};
    #pragma unroll
    for (int s = 0; s < NSPLIT; ++s) {
        lt += pl[(t * NSPLIT + s) * 32 + q];
        const bf16x4 pv = *(const bf16x4*)(pO + (t * NSPLIT + s) * 1024 + q * 32 + cq);
        #pragma unroll
        for (int i = 0; i < 4; ++i) o[i] += (float)pv[i];
    }
    const float linv = 1.0f / lt;
    #pragma unroll
    for (int i = 0; i < 4; ++i) o[i] = o[i] * linv + bl[cq + i];

    const int px = qt * 32 + q;
    const int py = px / WIMG, pxx = px % WIMG;
    const __bf16* vtb = vT + ((size_t)b * NPIX) * CCH + c0h + cq;
    #pragma unroll
    for (int dy = 0; dy < 5; ++dy) {
        const int yy = py + dy - 2;
        if (yy < 0 || yy >= WIMG) continue;
        #pragma unroll
        for (int dx = 0; dx < 5; ++dx) {
            const int xx = pxx + dx - 2;
            if (xx < 0 || xx >= WIMG) continue;
            const bf16x4 vv = *(const bf16x4*)(vtb + (size_t)(yy * WIMG + xx) * CCH);
            const int tap = dy * 5 + dx;
            #pragma unroll
            for (int i = 0; i < 4; ++i) o[i] += (float)vv[i] * wl[cq + i][tap];
        }
    }
    bf16x4 ov = {(__bf16)o[0], (__bf16)o[1], (__bf16)o[2], (__bf16)o[3]};
    *(bf16x4*)(attnT + ((size_t)(b * NPIX + px)) * CCH + c0h + cq) = ov;
}

// ---------------------------------------------------------------------------
// K4: out = proj_w @ (attn+lepe) + proj_b, bf16 MFMA, zero LDS.
// grid (98, 4, 2) = 784 blocks, block 256; wave tile = 16 outputs x 16 px.
// ---------------------------------------------------------------------------
__global__ __launch_bounds__(256) void k_proj(
    const __bf16* __restrict__ attnT, const float* __restrict__ proj_w,
    const float* __restrict__ proj_b, float* __restrict__ out)
{
    const int tid = threadIdx.x;
    const int w = tid >> 6, lane = tid & 63;
    const int col = lane & 15, g = lane >> 4;
    const int px0 = blockIdx.x * 32 + (w >> 1) * 16;
    const int obase = blockIdx.y * 32 + (w & 1) * 16;
    const int b = blockIdx.z;

    const float* wrow = proj_w + (size_t)(obase + col) * CCH;
    const __bf16* abase = attnT + (size_t)(b * NPIX + px0) * CCH;

    f32x4 acc = {0.f, 0.f, 0.f, 0.f};
    #pragma unroll
    for (int ks = 0; ks < 4; ++ks) {
        const int c0 = ks * 32 + g * 8;
        const float4 wA = *(const float4*)(wrow + c0);
        const float4 wB = *(const float4*)(wrow + c0 + 4);
        bf16x8 af = {(__bf16)wA.x, (__bf16)wA.y, (__bf16)wA.z, (__bf16)wA.w,
                     (__bf16)wB.x, (__bf16)wB.y, (__bf16)wB.z, (__bf16)wB.w};
        const bf16x8 bf_ = *(const bf16x8*)(abase + (size_t)col * CCH + c0);
        acc = __builtin_amdgcn_mfma_f32_16x16x32_bf16(af, bf_, acc, 0, 0, 0);
    }

    const f32x4 pb = *(const f32x4*)(proj_b + obase + g * 4);
    #pragma unroll
    for (int r = 0; r < 4; ++r)
        out[(size_t)(b * CCH + obase + g * 4 + r) * NPIX + px0 + col] = acc[r] + pb[r];
}

// ---------------------------------------------------------------------------
extern "C" void kernel_launch(void* const* d_in, const int* in_sizes, int n_in,
                              void* d_out, int out_size, void* d_ws, size_t ws_size,
                              hipStream_t stream)
{
    const float* x      = (const float*)d_in[0];
    const float* qkv_w  = (const float*)d_in[1];
    const float* qkv_b  = (const float*)d_in[2];
    const float* lepe_w = (const float*)d_in[3];
    const float* lepe_b = (const float*)d_in[4];
    const float* proj_w = (const float*)d_in[5];
    const float* proj_b = (const float*)d_in[6];
    float* out = (float*)d_out;

    char* p = (char*)d_ws;                                   // ~15 MB total
    __bf16* qT    = (__bf16*)p;  p += (size_t)2 * NH * NPIX * HD * 2;   // 1.6 MB
    __bf16* kT    = (__bf16*)p;  p += (size_t)2 * NH * NPIX * HD * 2;   // 1.6 MB
    __bf16* vT    = (__bf16*)p;  p += (size_t)2 * NPIX * CCH * 2;       // 1.6 MB
    __bf16* vP    = (__bf16*)p;  p += (size_t)2 * CCH * NPIX * 2;       // 1.6 MB
    __bf16* attnT = (__bf16*)p;  p += (size_t)2 * NPIX * CCH * 2;       // 1.6 MB
    __bf16* pO    = (__bf16*)p;  p += (size_t)784 * NSPLIT * 1024 * 2;  // 6.4 MB
    float*  pl    = (float*)p;                                          // 0.4 MB

    k_qkv   <<<dim3(49, 3, 2), dim3(256), 0, stream>>>(x, qkv_w, qkv_b, qT, kT, vT, vP);
    k_attn  <<<dim3(49, 8, 2), dim3(256), 0, stream>>>(qT, kT, vP, pO, pl);
    k_reduce<<<dim3(98, 8),    dim3(256), 0, stream>>>(pO, pl, vT, lepe_w, lepe_b, attnT);
    k_proj  <<<dim3(98, 4, 2), dim3(256), 0, stream>>>(attnT, proj_w, proj_b, out);
}

// Round 9
// 123.225 us; speedup vs baseline: 16.4137x; 1.0809x over previous
//
#include <hip/hip_runtime.h>

typedef __bf16 bf16x8 __attribute__((ext_vector_type(8)));
typedef __bf16 bf16x4 __attribute__((ext_vector_type(4)));
typedef float  f32x4  __attribute__((ext_vector_type(4)));

#define NPIX  3136      // 56*56 = 49*64 (no tails)
#define WIMG  56
#define CCH   128
#define NH    4
#define HD    32
#define NSPLIT 8        // key-splits per (head, 64q) tile
// 32^-0.5 * log2(e): q pre-scaled so softmax uses exp2 directly
#define QSCALE 0.2550565470841439f

#if __has_builtin(__builtin_amdgcn_exp2f)
#define FEXP2(x) __builtin_amdgcn_exp2f(x)
#else
#define FEXP2(x) __expf((x) * 0.6931471805599453f)
#endif

// MFMA 16x16x32 maps (HW-verified R1-R8):
//   A[m=lane&15][k=(lane>>4)*8+j]   B[k=(lane>>4)*8+j][n=lane&15]
//   D: col(n)=lane&15, row(m)=(lane>>4)*4+reg
// A and B have the SAME lane->data map, so one fragment serves either role.
// Transpose-free attention (R8, correctness-verified): S^T = MFMA(A=K-frag,
// B=Q-frag) puts query on lane&15; with the pi key-slot permutation baked
// into kT rows and vP columns at k_qkv-write time, exp(S^T) registers ARE
// the PV B-fragments. No LDS in the K-loop.
// R7/R8 lesson: hot-loop fragments must be STATICALLY NAMED registers --
// no runtime-indexed arrays, no lambda pointer params (scratch demotion).

__device__ __forceinline__ int perm_inv(int k) {
    return (((k >> 5) & 1) * 2 + ((k >> 2) & 1)) * 16 + (((k >> 3) & 3) * 4) + (k & 3);
}

// ---------------------------------------------------------------------------
// K1: qkv = qkv_w @ x + qkv_b, bf16 MFMA (M=384, K=128, N=6272).  (R8 kernel)
// grid (49, 3, 2), block 256. kT rows / vP columns written pi-permuted.
// ---------------------------------------------------------------------------
__global__ __launch_bounds__(256) void k_qkv(
    const float* __restrict__ x, const float* __restrict__ qkv_w,
    const float* __restrict__ qkv_b,
    __bf16* __restrict__ qT, __bf16* __restrict__ kT,
    __bf16* __restrict__ vT, __bf16* __restrict__ vP)
{
    __shared__ __bf16 xl[64][136];                 // [px][c], row stride 272B
    const int tid = threadIdx.x;
    const int w = tid >> 6, lane = tid & 63;
    const int col = lane & 15, g = lane >> 4;
    const int px0 = blockIdx.x * 64;
    const int slab = blockIdx.y;                   // 0 q, 1 k, 2 v
    const int b = blockIdx.z;
    const int obase = slab * 128 + w * 32;

    {   // stage x tile (coalesced dword loads, packed b64 LDS writes)
        const int px = tid & 63, cq = tid >> 6;
        const float* xp = x + (size_t)b * CCH * NPIX + px0 + px;
        #pragma unroll
        for (int i = 0; i < 8; ++i) {
            const int c0 = cq * 4 + i * 16;
            const float v0 = xp[(size_t)(c0 + 0) * NPIX];
            const float v1 = xp[(size_t)(c0 + 1) * NPIX];
            const float v2 = xp[(size_t)(c0 + 2) * NPIX];
            const float v3 = xp[(size_t)(c0 + 3) * NPIX];
            bf16x4 bv = {(__bf16)v0, (__bf16)v1, (__bf16)v2, (__bf16)v3};
            *(bf16x4*)&xl[px][c0] = bv;
        }
    }
    __syncthreads();

    f32x4 acc[2][4];                               // [out tile][px tile]
    #pragma unroll
    for (int ot = 0; ot < 2; ++ot)
        #pragma unroll
        for (int a = 0; a < 4; ++a) acc[ot][a] = (f32x4){0.f, 0.f, 0.f, 0.f};

    #pragma unroll
    for (int ks = 0; ks < 4; ++ks) {
        const int c0 = ks * 32 + g * 8;
        #pragma unroll
        for (int ot = 0; ot < 2; ++ot) {
            const float* wrow = qkv_w + (size_t)(obase + ot * 16 + col) * CCH + c0;
            const float4 wA = *(const float4*)(wrow);
            const float4 wB = *(const float4*)(wrow + 4);
            bf16x8 af = {(__bf16)wA.x, (__bf16)wA.y, (__bf16)wA.z, (__bf16)wA.w,
                         (__bf16)wB.x, (__bf16)wB.y, (__bf16)wB.z, (__bf16)wB.w};
            #pragma unroll
            for (int a = 0; a < 4; ++a) {
                const bf16x8 bf_ = *(const bf16x8*)&xl[16 * a + col][c0];  // one b128
                acc[ot][a] = __builtin_amdgcn_mfma_f32_16x16x32_bf16(af, bf_, acc[ot][a], 0, 0, 0);
            }
        }
    }

    #pragma unroll
    for (int ot = 0; ot < 2; ++ot) {
        const int orow = obase + ot * 16 + g * 4;      // global output row
        const f32x4 bias4 = *(const f32x4*)(qkv_b + orow);
        if (slab == 0) {                               // ---- q (scaled) ----
            const int o = orow, h = o >> 5, d0 = o & 31;
            __bf16* dst = qT + ((size_t)(b * NH + h) * NPIX) * HD + d0;
            #pragma unroll
            for (int a = 0; a < 4; ++a) {
                const int px = px0 + 16 * a + col;
                bf16x4 v;
                #pragma unroll
                for (int r = 0; r < 4; ++r) v[r] = (__bf16)((acc[ot][a][r] + bias4[r]) * QSCALE);
                *(bf16x4*)(dst + (size_t)px * HD) = v;
            }
        } else if (slab == 1) {                        // ---- k (pi-permuted rows) ----
            const int o = orow - 128, h = o >> 5, d0 = o & 31;
            __bf16* dst = kT + ((size_t)(b * NH + h) * NPIX) * HD + d0;
            #pragma unroll
            for (int a = 0; a < 4; ++a) {
                const int s = perm_inv(16 * a + col);  // slot for key kappa
                bf16x4 v;
                #pragma unroll
                for (int r = 0; r < 4; ++r) v[r] = (__bf16)(acc[ot][a][r] + bias4[r]);
                *(bf16x4*)(dst + (size_t)(px0 + s) * HD) = v;
            }
        } else {                                       // ---- v: vT + pi-permuted vP ----
            const int c = orow - 256;
            #pragma unroll
            for (int a = 0; a < 4; ++a) {
                const int px = px0 + 16 * a + col;
                const int s = perm_inv(16 * a + col);
                bf16x4 v;
                #pragma unroll
                for (int r = 0; r < 4; ++r) v[r] = (__bf16)(acc[ot][a][r] + bias4[r]);
                *(bf16x4*)(vT + ((size_t)(b * NPIX + px)) * CCH + c) = v;
                #pragma unroll
                for (int r = 0; r < 4; ++r)
                    vP[((size_t)(b * CCH + c + r)) * NPIX + px0 + s] = v[r];
            }
        }
    }
}

// ---------------------------------------------------------------------------
// K2: attention partials. 64 QUERIES PER WAVE (halves K/V L2 traffic to
// 157 MB), transpose-free, zero LDS, all hot-loop state in NAMED registers.
// grid (49, 8, 2), block 256 = 4 indep waves; wave -> sp = 4*bz + w.
// Per chunk: 8 b128 loads, 40 MFMA, 64 exp. Outputs UNNORMALIZED partials:
// pO bf16 [t=bh*49+qt][sp][q 64][d 32], pl f32 [t][sp][q 64].
// ---------------------------------------------------------------------------
__global__ __launch_bounds__(256) void k_attn(
    const __bf16* __restrict__ qT, const __bf16* __restrict__ kT,
    const __bf16* __restrict__ vP,
    __bf16* __restrict__ pO, float* __restrict__ pl)
{
    const int tid = threadIdx.x;
    const int w = tid >> 6, lane = tid & 63;
    const int col = lane & 15, g = lane >> 4;
    const int qt = blockIdx.x;
    const int bh = blockIdx.y;
    const int sp = blockIdx.z * 4 + w;
    const int b = bh >> 2, h = bh & 3;
    const int qbase = qt * 64;
    const size_t headoff = (size_t)bh * NPIX * HD;
    const int c0h = h * HD;

    // 4 Q fragments (usable as MFMA B operands; same lane map as A)
    const __bf16* qbp = qT + headoff + (size_t)(qbase + col) * HD + g * 8;
    const bf16x8 aq0 = *(const bf16x8*)(qbp);
    const bf16x8 aq1 = *(const bf16x8*)(qbp + 16 * HD);
    const bf16x8 aq2 = *(const bf16x8*)(qbp + 32 * HD);
    const bf16x8 aq3 = *(const bf16x8*)(qbp + 48 * HD);

    const __bf16 one = (__bf16)1.0f;
    const bf16x8 ones = {one, one, one, one, one, one, one, one};

    f32x4 O00 = {0,0,0,0}, O01 = {0,0,0,0}, O10 = {0,0,0,0}, O11 = {0,0,0,0};
    f32x4 O20 = {0,0,0,0}, O21 = {0,0,0,0}, O30 = {0,0,0,0}, O31 = {0,0,0,0};
    f32x4 La0 = {0,0,0,0}, La1 = {0,0,0,0}, La2 = {0,0,0,0}, La3 = {0,0,0,0};

    const __bf16* kTh   = kT + headoff;
    const __bf16* vrow0 = vP + (size_t)(b * CCH + c0h + col)      * NPIX;  // d = col
    const __bf16* vrow1 = vP + (size_t)(b * CCH + c0h + 16 + col) * NPIX;  // d = col+16

    const int cs = (49 * sp) >> 3, ce = (49 * (sp + 1)) >> 3;   // 6 or 7 chunks

#define LOADK4(K0R, K1R, K2R, K3R, CHUNK) do { const int _k0 = (CHUNK) * 64;           \
        K0R = *(const bf16x8*)(kTh + (size_t)(_k0      + col) * HD + g * 8);           \
        K1R = *(const bf16x8*)(kTh + (size_t)(_k0 + 16 + col) * HD + g * 8);           \
        K2R = *(const bf16x8*)(kTh + (size_t)(_k0 + 32 + col) * HD + g * 8);           \
        K3R = *(const bf16x8*)(kTh + (size_t)(_k0 + 48 + col) * HD + g * 8); } while (0)

    // one query-half: S^T MFMAs -> exp/pack -> PV + L MFMAs (all named regs)
#define SQH(AQ, O0R, O1R, LAR)  do {                                                   \
        f32x4 s0 = __builtin_amdgcn_mfma_f32_16x16x32_bf16(ck0, AQ, zz, 0, 0, 0);      \
        f32x4 s1 = __builtin_amdgcn_mfma_f32_16x16x32_bf16(ck1, AQ, zz, 0, 0, 0);      \
        f32x4 s2 = __builtin_amdgcn_mfma_f32_16x16x32_bf16(ck2, AQ, zz, 0, 0, 0);      \
        f32x4 s3 = __builtin_amdgcn_mfma_f32_16x16x32_bf16(ck3, AQ, zz, 0, 0, 0);      \
        bf16x8 P0 = {(__bf16)FEXP2(s0[0]), (__bf16)FEXP2(s0[1]),                       \
                     (__bf16)FEXP2(s0[2]), (__bf16)FEXP2(s0[3]),                       \
                     (__bf16)FEXP2(s1[0]), (__bf16)FEXP2(s1[1]),                       \
                     (__bf16)FEXP2(s1[2]), (__bf16)FEXP2(s1[3])};                      \
        bf16x8 P1 = {(__bf16)FEXP2(s2[0]), (__bf16)FEXP2(s2[1]),                       \
                     (__bf16)FEXP2(s2[2]), (__bf16)FEXP2(s2[3]),                       \
                     (__bf16)FEXP2(s3[0]), (__bf16)FEXP2(s3[1]),                       \
                     (__bf16)FEXP2(s3[2]), (__bf16)FEXP2(s3[3])};                      \
        O0R = __builtin_amdgcn_mfma_f32_16x16x32_bf16(vv00, P0, O0R, 0, 0, 0);         \
        O0R = __builtin_amdgcn_mfma_f32_16x16x32_bf16(vv01, P1, O0R, 0, 0, 0);         \
        O1R = __builtin_amdgcn_mfma_f32_16x16x32_bf16(vv10, P0, O1R, 0, 0, 0);         \
        O1R = __builtin_amdgcn_mfma_f32_16x16x32_bf16(vv11, P1, O1R, 0, 0, 0);         \
        LAR = __builtin_amdgcn_mfma_f32_16x16x32_bf16(ones, P0, LAR, 0, 0, 0);         \
        LAR = __builtin_amdgcn_mfma_f32_16x16x32_bf16(ones, P1, LAR, 0, 0, 0);         \
    } while (0)

#define CHUNK_STEP(K0R, K1R, K2R, K3R, CHUNK) do {                                     \
        const int _kv0 = (CHUNK) * 64;                                                 \
        const bf16x8 vv00 = *(const bf16x8*)(vrow0 + _kv0      + g * 8);               \
        const bf16x8 vv01 = *(const bf16x8*)(vrow0 + _kv0 + 32 + g * 8);               \
        const bf16x8 vv10 = *(const bf16x8*)(vrow1 + _kv0      + g * 8);               \
        const bf16x8 vv11 = *(const bf16x8*)(vrow1 + _kv0 + 32 + g * 8);               \
        const bf16x8 ck0 = K0R, ck1 = K1R, ck2 = K2R, ck3 = K3R;                       \
        const f32x4 zz = {0.f, 0.f, 0.f, 0.f};                                         \
        SQH(aq0, O00, O01, La0);                                                       \
        SQH(aq1, O10, O11, La1);                                                       \
        SQH(aq2, O20, O21, La2);                                                       \
        SQH(aq3, O30, O31, La3);                                                       \
    } while (0)

    bf16x8 ka0, ka1, ka2, ka3, kb0, kb1, kb2, kb3;
    LOADK4(ka0, ka1, ka2, ka3, cs);
    int cc = cs;
    while (cc + 2 <= ce) {                      // static ping-pong (named regs)
        LOADK4(kb0, kb1, kb2, kb3, cc + 1);
        CHUNK_STEP(ka0, ka1, ka2, ka3, cc);
        LOADK4(ka0, ka1, ka2, ka3, (cc + 2 < ce) ? cc + 2 : cs);   // dummy ok
        CHUNK_STEP(kb0, kb1, kb2, kb3, cc + 1);
        cc += 2;
    }
    if (cc < ce) CHUNK_STEP(ka0, ka1, ka2, ka3, cc);   // odd tail (7-chunk split)
#undef LOADK4
#undef SQH
#undef CHUNK_STEP

    // store partials: D-layout col=q(16), row=d_local=4g+r; q = QH*16+col
    const int t = bh * 49 + qt;
    __bf16* po = pO + ((size_t)t * NSPLIT + sp) * 64 * 32;
    float* plp = pl + ((size_t)t * NSPLIT + sp) * 64;
#define STQH(QH, O0R, O1R, LAR) do {                                                   \
        bf16x4 v0 = {(__bf16)O0R[0], (__bf16)O0R[1], (__bf16)O0R[2], (__bf16)O0R[3]};  \
        bf16x4 v1 = {(__bf16)O1R[0], (__bf16)O1R[1], (__bf16)O1R[2], (__bf16)O1R[3]};  \
        *(bf16x4*)(po + ((QH) * 16 + col) * 32      + g * 4) = v0;                     \
        *(bf16x4*)(po + ((QH) * 16 + col) * 32 + 16 + g * 4) = v1;                     \
        if (g == 0) plp[(QH) * 16 + col] = LAR[0];                                     \
    } while (0)
    STQH(0, O00, O01, La0);
    STQH(1, O10, O11, La1);
    STQH(2, O20, O21, La2);
    STQH(3, O30, O31, La3);
#undef STQH
}

// ---------------------------------------------------------------------------
// K3: reduce 8 split partials + normalize + LePE + bias -> attnT [b][px][c].
// grid (49, 8) = 392 blocks, block 256: thread = (q 0..63, 8-channel group).
// All pO reads are 16B contiguous; wave covers 1KB contiguous.
// ---------------------------------------------------------------------------
__global__ __launch_bounds__(256) void k_reduce(
    const __bf16* __restrict__ pO, const float* __restrict__ pl,
    const __bf16* __restrict__ vT,
    const float* __restrict__ lepe_w, const float* __restrict__ lepe_b,
    __bf16* __restrict__ attnT)
{
    __shared__ float wl[32][25];
    __shared__ float bl[32];
    const int tid = threadIdx.x;
    const int qt = blockIdx.x, bh = blockIdx.y;
    const int b = bh >> 2, h = bh & 3;
    const int c0h = h * HD;

    for (int i = tid; i < 800; i += 256) ((float*)wl)[i] = lepe_w[c0h * 25 + i];
    if (tid < 32) bl[tid] = lepe_b[c0h + tid];
    __syncthreads();

    const int q  = tid >> 2;                   // 0..63
    const int dg = (tid & 3) * 8;              // 0,8,16,24
    const size_t t = (size_t)bh * 49 + qt;

    float lt = 0.f;
    float o[8] = {0.f, 0.f, 0.f, 0.f, 0.f, 0.f, 0.f, 0.f};
    #pragma unroll
    for (int s = 0; s < NSPLIT; ++s) {
        lt += pl[(t * NSPLIT + s) * 64 + q];
        const bf16x8 pv = *(const bf16x8*)(pO + ((t * NSPLIT + s) * 64 + q) * 32 + dg);
        #pragma unroll
        for (int i = 0; i < 8; ++i) o[i] += (float)pv[i];
    }
    const float linv = 1.0f / lt;
    #pragma unroll
    for (int i = 0; i < 8; ++i) o[i] = o[i] * linv + bl[dg + i];

    const int px = qt * 64 + q;
    const int py = px / WIMG, pxx = px % WIMG;
    const __bf16* vtb = vT + ((size_t)b * NPIX) * CCH + c0h + dg;
    #pragma unroll
    for (int dy = 0; dy < 5; ++dy) {
        const int yy = py + dy - 2;
        if (yy < 0 || yy >= WIMG) continue;
        #pragma unroll
        for (int dx = 0; dx < 5; ++dx) {
            const int xx = pxx + dx - 2;
            if (xx < 0 || xx >= WIMG) continue;
            const bf16x8 vv = *(const bf16x8*)(vtb + (size_t)(yy * WIMG + xx) * CCH);
            const int tap = dy * 5 + dx;
            #pragma unroll
            for (int i = 0; i < 8; ++i) o[i] += (float)vv[i] * wl[dg + i][tap];
        }
    }
    bf16x8 ov = {(__bf16)o[0], (__bf16)o[1], (__bf16)o[2], (__bf16)o[3],
                 (__bf16)o[4], (__bf16)o[5], (__bf16)o[6], (__bf16)o[7]};
    *(bf16x8*)(attnT + ((size_t)(b * NPIX + px)) * CCH + c0h + dg) = ov;
}

// ---------------------------------------------------------------------------
// K4: out = proj_w @ (attn+lepe) + proj_b, bf16 MFMA, zero LDS.  (R8 kernel)
// grid (98, 4, 2) = 784 blocks, block 256; wave tile = 16 outputs x 16 px.
// ---------------------------------------------------------------------------
__global__ __launch_bounds__(256) void k_proj(
    const __bf16* __restrict__ attnT, const float* __restrict__ proj_w,
    const float* __restrict__ proj_b, float* __restrict__ out)
{
    const int tid = threadIdx.x;
    const int w = tid >> 6, lane = tid & 63;
    const int col = lane & 15, g = lane >> 4;
    const int px0 = blockIdx.x * 32 + (w >> 1) * 16;
    const int obase = blockIdx.y * 32 + (w & 1) * 16;
    const int b = blockIdx.z;

    const float* wrow = proj_w + (size_t)(obase + col) * CCH;
    const __bf16* abase = attnT + (size_t)(b * NPIX + px0) * CCH;

    f32x4 acc = {0.f, 0.f, 0.f, 0.f};
    #pragma unroll
    for (int ks = 0; ks < 4; ++ks) {
        const int c0 = ks * 32 + g * 8;
        const float4 wA = *(const float4*)(wrow + c0);
        const float4 wB = *(const float4*)(wrow + c0 + 4);
        bf16x8 af = {(__bf16)wA.x, (__bf16)wA.y, (__bf16)wA.z, (__bf16)wA.w,
                     (__bf16)wB.x, (__bf16)wB.y, (__bf16)wB.z, (__bf16)wB.w};
        const bf16x8 bf_ = *(const bf16x8*)(abase + (size_t)col * CCH + c0);
        acc = __builtin_amdgcn_mfma_f32_16x16x32_bf16(af, bf_, acc, 0, 0, 0);
    }

    const f32x4 pb = *(const f32x4*)(proj_b + obase + g * 4);
    #pragma unroll
    for (int r = 0; r < 4; ++r)
        out[(size_t)(b * CCH + obase + g * 4 + r) * NPIX + px0 + col] = acc[r] + pb[r];
}

// ---------------------------------------------------------------------------
extern "C" void kernel_launch(void* const* d_in, const int* in_sizes, int n_in,
                              void* d_out, int out_size, void* d_ws, size_t ws_size,
                              hipStream_t stream)
{
    const float* x      = (const float*)d_in[0];
    const float* qkv_w  = (const float*)d_in[1];
    const float* qkv_b  = (const float*)d_in[2];
    const float* lepe_w = (const float*)d_in[3];
    const float* lepe_b = (const float*)d_in[4];
    const float* proj_w = (const float*)d_in[5];
    const float* proj_b = (const float*)d_in[6];
    float* out = (float*)d_out;

    char* p = (char*)d_ws;                                   // ~22 MB total
    __bf16* qT    = (__bf16*)p;  p += (size_t)2 * NH * NPIX * HD * 2;       // 1.6 MB
    __bf16* kT    = (__bf16*)p;  p += (size_t)2 * NH * NPIX * HD * 2;       // 1.6 MB
    __bf16* vT    = (__bf16*)p;  p += (size_t)2 * NPIX * CCH * 2;           // 1.6 MB
    __bf16* vP    = (__bf16*)p;  p += (size_t)2 * CCH * NPIX * 2;           // 1.6 MB
    __bf16* attnT = (__bf16*)p;  p += (size_t)2 * NPIX * CCH * 2;           // 1.6 MB
    __bf16* pO    = (__bf16*)p;  p += (size_t)392 * NSPLIT * 64 * 32 * 2;   // 12.8 MB
    float*  pl    = (float*)p;                                              // 0.8 MB

    k_qkv   <<<dim3(49, 3, 2), dim3(256), 0, stream>>>(x, qkv_w, qkv_b, qT, kT, vT, vP);
    k_attn  <<<dim3(49, 8, 2), dim3(256), 0, stream>>>(qT, kT, vP, pO, pl);
    k_reduce<<<dim3(49, 8),    dim3(256), 0, stream>>>(pO, pl, vT, lepe_w, lepe_b, attnT);
    k_proj  <<<dim3(98, 4, 2), dim3(256), 0, stream>>>(attnT, proj_w, proj_b, out);
}

// Round 10
// 122.019 us; speedup vs baseline: 16.5760x; 1.0099x over previous
//
#include <hip/hip_runtime.h>

typedef __bf16 bf16x8 __attribute__((ext_vector_type(8)));
typedef __bf16 bf16x4 __attribute__((ext_vector_type(4)));
typedef float  f32x4  __attribute__((ext_vector_type(4)));

#define NPIX  3136      // 56*56 = 49*64 (no tails)
#define WIMG  56
#define CCH   128
#define NH    4
#define HD    32
#define NSPLIT 8        // key-splits per (head, 64q) tile
// 32^-0.5 * log2(e): q pre-scaled so softmax uses exp2 directly
#define QSCALE 0.2550565470841439f

#if __has_builtin(__builtin_amdgcn_exp2f)
#define FEXP2(x) __builtin_amdgcn_exp2f(x)
#else
#define FEXP2(x) __expf((x) * 0.6931471805599453f)
#endif

// MFMA 16x16x32 maps (HW-verified R1-R9):
//   A[m=lane&15][k=(lane>>4)*8+j]   B[k=(lane>>4)*8+j][n=lane&15]
//   D: col(n)=lane&15, row(m)=(lane>>4)*4+reg
// A and B share the same lane->data map (one fragment serves either role).
// Transpose-free attention (R8/R9-verified): S^T = MFMA(A=K-frag, B=Q-frag)
// puts query on lane&15; with the pi key-slot permutation baked into kT rows
// and vP columns at k_qkv-write time, exp(S^T) registers ARE the PV B-frags.
// R7 lesson: hot-loop fragments = statically named registers only.
// R10: K/V chunks staged once per 4-wave block in double-buffered LDS
// (4x less L2 traffic than R9's per-wave reads -- attn was L2-BW-bound).

__device__ __forceinline__ int perm_inv(int k) {
    return (((k >> 5) & 1) * 2 + ((k >> 2) & 1)) * 16 + (((k >> 3) & 3) * 4) + (k & 3);
}

// ---------------------------------------------------------------------------
// K1: qkv = qkv_w @ x + qkv_b, bf16 MFMA (M=384, K=128, N=6272).  (R9 kernel)
// grid (49, 3, 2), block 256. kT rows / vP columns written pi-permuted.
// ---------------------------------------------------------------------------
__global__ __launch_bounds__(256) void k_qkv(
    const float* __restrict__ x, const float* __restrict__ qkv_w,
    const float* __restrict__ qkv_b,
    __bf16* __restrict__ qT, __bf16* __restrict__ kT,
    __bf16* __restrict__ vT, __bf16* __restrict__ vP)
{
    __shared__ __bf16 xl[64][136];                 // [px][c], row stride 272B
    const int tid = threadIdx.x;
    const int w = tid >> 6, lane = tid & 63;
    const int col = lane & 15, g = lane >> 4;
    const int px0 = blockIdx.x * 64;
    const int slab = blockIdx.y;                   // 0 q, 1 k, 2 v
    const int b = blockIdx.z;
    const int obase = slab * 128 + w * 32;

    {   // stage x tile (coalesced dword loads, packed b64 LDS writes)
        const int px = tid & 63, cq = tid >> 6;
        const float* xp = x + (size_t)b * CCH * NPIX + px0 + px;
        #pragma unroll
        for (int i = 0; i < 8; ++i) {
            const int c0 = cq * 4 + i * 16;
            const float v0 = xp[(size_t)(c0 + 0) * NPIX];
            const float v1 = xp[(size_t)(c0 + 1) * NPIX];
            const float v2 = xp[(size_t)(c0 + 2) * NPIX];
            const float v3 = xp[(size_t)(c0 + 3) * NPIX];
            bf16x4 bv = {(__bf16)v0, (__bf16)v1, (__bf16)v2, (__bf16)v3};
            *(bf16x4*)&xl[px][c0] = bv;
        }
    }
    __syncthreads();

    f32x4 acc[2][4];                               // [out tile][px tile]
    #pragma unroll
    for (int ot = 0; ot < 2; ++ot)
        #pragma unroll
        for (int a = 0; a < 4; ++a) acc[ot][a] = (f32x4){0.f, 0.f, 0.f, 0.f};

    #pragma unroll
    for (int ks = 0; ks < 4; ++ks) {
        const int c0 = ks * 32 + g * 8;
        #pragma unroll
        for (int ot = 0; ot < 2; ++ot) {
            const float* wrow = qkv_w + (size_t)(obase + ot * 16 + col) * CCH + c0;
            const float4 wA = *(const float4*)(wrow);
            const float4 wB = *(const float4*)(wrow + 4);
            bf16x8 af = {(__bf16)wA.x, (__bf16)wA.y, (__bf16)wA.z, (__bf16)wA.w,
                         (__bf16)wB.x, (__bf16)wB.y, (__bf16)wB.z, (__bf16)wB.w};
            #pragma unroll
            for (int a = 0; a < 4; ++a) {
                const bf16x8 bf_ = *(const bf16x8*)&xl[16 * a + col][c0];  // one b128
                acc[ot][a] = __builtin_amdgcn_mfma_f32_16x16x32_bf16(af, bf_, acc[ot][a], 0, 0, 0);
            }
        }
    }

    #pragma unroll
    for (int ot = 0; ot < 2; ++ot) {
        const int orow = obase + ot * 16 + g * 4;      // global output row
        const f32x4 bias4 = *(const f32x4*)(qkv_b + orow);
        if (slab == 0) {                               // ---- q (scaled) ----
            const int o = orow, h = o >> 5, d0 = o & 31;
            __bf16* dst = qT + ((size_t)(b * NH + h) * NPIX) * HD + d0;
            #pragma unroll
            for (int a = 0; a < 4; ++a) {
                const int px = px0 + 16 * a + col;
                bf16x4 v;
                #pragma unroll
                for (int r = 0; r < 4; ++r) v[r] = (__bf16)((acc[ot][a][r] + bias4[r]) * QSCALE);
                *(bf16x4*)(dst + (size_t)px * HD) = v;
            }
        } else if (slab == 1) {                        // ---- k (pi-permuted rows) ----
            const int o = orow - 128, h = o >> 5, d0 = o & 31;
            __bf16* dst = kT + ((size_t)(b * NH + h) * NPIX) * HD + d0;
            #pragma unroll
            for (int a = 0; a < 4; ++a) {
                const int s = perm_inv(16 * a + col);  // slot for key kappa
                bf16x4 v;
                #pragma unroll
                for (int r = 0; r < 4; ++r) v[r] = (__bf16)(acc[ot][a][r] + bias4[r]);
                *(bf16x4*)(dst + (size_t)(px0 + s) * HD) = v;
            }
        } else {                                       // ---- v: vT + pi-permuted vP ----
            const int c = orow - 256;
            #pragma unroll
            for (int a = 0; a < 4; ++a) {
                const int px = px0 + 16 * a + col;
                const int s = perm_inv(16 * a + col);
                bf16x4 v;
                #pragma unroll
                for (int r = 0; r < 4; ++r) v[r] = (__bf16)(acc[ot][a][r] + bias4[r]);
                *(bf16x4*)(vT + ((size_t)(b * NPIX + px)) * CCH + c) = v;
                #pragma unroll
                for (int r = 0; r < 4; ++r)
                    vP[((size_t)(b * CCH + c + r)) * NPIX + px0 + s] = v[r];
            }
        }
    }
}

// ---------------------------------------------------------------------------
// K2: attention partials. Block = 4 waves = 4 adjacent 64-q tiles sharing one
// split's chunk stream; K/V chunk staged ONCE per block into double-buffered
// LDS (L2 traffic 157 MB -> 41 MB; attn was L2-BW-bound per R8->R9 delta).
// grid (13, 8, 8): qt = 4*bx + w (>=49 -> idle wave: stages+barriers, no
// store), bh = by, sp = bz. One __syncthreads per chunk. Transpose-free math
// identical to R9. Outputs UNNORMALIZED: pO bf16 [t][sp][q 64][d 32], pl f32.
// ---------------------------------------------------------------------------
__global__ __launch_bounds__(256) void k_attn(
    const __bf16* __restrict__ qT, const __bf16* __restrict__ kT,
    const __bf16* __restrict__ vP,
    __bf16* __restrict__ pO, float* __restrict__ pl)
{
    __shared__ __bf16 Kl[2][64][32];       // [buf][slot][d] -- source layout
    __shared__ __bf16 Vl[2][32][72];       // [buf][d][slot], +8 pad (banks, 16B rows)

    const int tid = threadIdx.x;
    const int w = tid >> 6, lane = tid & 63;
    const int col = lane & 15, g = lane >> 4;
    const int qt = blockIdx.x * 4 + w;          // 0..51; 49..51 idle
    const bool valid = qt < 49;
    const int qtc = valid ? qt : 48;
    const int bh = blockIdx.y, sp = blockIdx.z;
    const int b = bh >> 2, h = bh & 3;
    const int qbase = qtc * 64;
    const size_t headoff = (size_t)bh * NPIX * HD;
    const int c0h = h * HD;

    // 4 Q fragments (MFMA B operands)
    const __bf16* qbp = qT + headoff + (size_t)(qbase + col) * HD + g * 8;
    const bf16x8 aq0 = *(const bf16x8*)(qbp);
    const bf16x8 aq1 = *(const bf16x8*)(qbp + 16 * HD);
    const bf16x8 aq2 = *(const bf16x8*)(qbp + 32 * HD);
    const bf16x8 aq3 = *(const bf16x8*)(qbp + 48 * HD);

    const __bf16 one = (__bf16)1.0f;
    const bf16x8 ones = {one, one, one, one, one, one, one, one};

    f32x4 O00 = {0,0,0,0}, O01 = {0,0,0,0}, O10 = {0,0,0,0}, O11 = {0,0,0,0};
    f32x4 O20 = {0,0,0,0}, O21 = {0,0,0,0}, O30 = {0,0,0,0}, O31 = {0,0,0,0};
    f32x4 La0 = {0,0,0,0}, La1 = {0,0,0,0}, La2 = {0,0,0,0}, La3 = {0,0,0,0};

    const __bf16* kTh = kT + headoff;
    // staging sources: K = linear 4KB/chunk; V = 32 rows x 128B/chunk
    const int vr = tid >> 3;                    // 0..31 (d row)
    const int vo = (tid & 7) * 8;               // elem offset within chunk
    const __bf16* vsrc = vP + (size_t)(b * CCH + c0h + vr) * NPIX + vo;

    const int cs = (49 * sp) >> 3, ce = (49 * (sp + 1)) >> 3;   // 6 or 7 chunks

#define STAGE(BUF, CHUNK) do { const int _k0 = (CHUNK) * 64;                           \
        *(bf16x8*)(&Kl[BUF][0][0] + tid * 8) =                                         \
            *(const bf16x8*)(kTh + (size_t)_k0 * HD + tid * 8);                        \
        *(bf16x8*)(&Vl[BUF][vr][vo]) = *(const bf16x8*)(vsrc + _k0);                   \
    } while (0)

#define SQH(AQ, O0R, O1R, LAR)  do {                                                   \
        f32x4 s0 = __builtin_amdgcn_mfma_f32_16x16x32_bf16(ck0, AQ, zz, 0, 0, 0);      \
        f32x4 s1 = __builtin_amdgcn_mfma_f32_16x16x32_bf16(ck1, AQ, zz, 0, 0, 0);      \
        f32x4 s2 = __builtin_amdgcn_mfma_f32_16x16x32_bf16(ck2, AQ, zz, 0, 0, 0);      \
        f32x4 s3 = __builtin_amdgcn_mfma_f32_16x16x32_bf16(ck3, AQ, zz, 0, 0, 0);      \
        bf16x8 P0 = {(__bf16)FEXP2(s0[0]), (__bf16)FEXP2(s0[1]),                       \
                     (__bf16)FEXP2(s0[2]), (__bf16)FEXP2(s0[3]),                       \
                     (__bf16)FEXP2(s1[0]), (__bf16)FEXP2(s1[1]),                       \
                     (__bf16)FEXP2(s1[2]), (__bf16)FEXP2(s1[3])};                      \
        bf16x8 P1 = {(__bf16)FEXP2(s2[0]), (__bf16)FEXP2(s2[1]),                       \
                     (__bf16)FEXP2(s2[2]), (__bf16)FEXP2(s2[3]),                       \
                     (__bf16)FEXP2(s3[0]), (__bf16)FEXP2(s3[1]),                       \
                     (__bf16)FEXP2(s3[2]), (__bf16)FEXP2(s3[3])};                      \
        O0R = __builtin_amdgcn_mfma_f32_16x16x32_bf16(vv00, P0, O0R, 0, 0, 0);         \
        O0R = __builtin_amdgcn_mfma_f32_16x16x32_bf16(vv01, P1, O0R, 0, 0, 0);         \
        O1R = __builtin_amdgcn_mfma_f32_16x16x32_bf16(vv10, P0, O1R, 0, 0, 0);         \
        O1R = __builtin_amdgcn_mfma_f32_16x16x32_bf16(vv11, P1, O1R, 0, 0, 0);         \
        LAR = __builtin_amdgcn_mfma_f32_16x16x32_bf16(ones, P0, LAR, 0, 0, 0);         \
        LAR = __builtin_amdgcn_mfma_f32_16x16x32_bf16(ones, P1, LAR, 0, 0, 0);         \
    } while (0)

#define COMPUTE(CUR) do {                                                              \
        const __bf16* Kb = &Kl[CUR][0][0];                                             \
        const __bf16* Vb = &Vl[CUR][0][0];                                             \
        const bf16x8 ck0 = *(const bf16x8*)(Kb + (      col) * 32 + g * 8);            \
        const bf16x8 ck1 = *(const bf16x8*)(Kb + (16 + col) * 32 + g * 8);             \
        const bf16x8 ck2 = *(const bf16x8*)(Kb + (32 + col) * 32 + g * 8);             \
        const bf16x8 ck3 = *(const bf16x8*)(Kb + (48 + col) * 32 + g * 8);             \
        const bf16x8 vv00 = *(const bf16x8*)(Vb + (      col) * 72      + g * 8);      \
        const bf16x8 vv01 = *(const bf16x8*)(Vb + (      col) * 72 + 32 + g * 8);      \
        const bf16x8 vv10 = *(const bf16x8*)(Vb + (16 + col) * 72      + g * 8);       \
        const bf16x8 vv11 = *(const bf16x8*)(Vb + (16 + col) * 72 + 32 + g * 8);       \
        const f32x4 zz = {0.f, 0.f, 0.f, 0.f};                                         \
        SQH(aq0, O00, O01, La0);                                                       \
        SQH(aq1, O10, O11, La1);                                                       \
        SQH(aq2, O20, O21, La2);                                                       \
        SQH(aq3, O30, O31, La3);                                                       \
    } while (0)

    STAGE(0, cs);
    __syncthreads();
    for (int cc = cs; cc < ce; ++cc) {
        const int cur = (cc - cs) & 1;
        if (cc + 1 < ce) STAGE(cur ^ 1, cc + 1);   // overlaps with compute(cur)
        COMPUTE(cur);
        __syncthreads();                           // staging done + cur consumed
    }
#undef STAGE
#undef SQH
#undef COMPUTE

    if (!valid) return;
    // store partials: D-layout col=q(16), row=d_local=4g+r; q = QH*16+col
    const int t = bh * 49 + qt;
    __bf16* po = pO + ((size_t)t * NSPLIT + sp) * 64 * 32;
    float* plp = pl + ((size_t)t * NSPLIT + sp) * 64;
#define STQH(QH, O0R, O1R, LAR) do {                                                   \
        bf16x4 v0 = {(__bf16)O0R[0], (__bf16)O0R[1], (__bf16)O0R[2], (__bf16)O0R[3]};  \
        bf16x4 v1 = {(__bf16)O1R[0], (__bf16)O1R[1], (__bf16)O1R[2], (__bf16)O1R[3]};  \
        *(bf16x4*)(po + ((QH) * 16 + col) * 32      + g * 4) = v0;                     \
        *(bf16x4*)(po + ((QH) * 16 + col) * 32 + 16 + g * 4) = v1;                     \
        if (g == 0) plp[(QH) * 16 + col] = LAR[0];                                     \
    } while (0)
    STQH(0, O00, O01, La0);
    STQH(1, O10, O11, La1);
    STQH(2, O20, O21, La2);
    STQH(3, O30, O31, La3);
#undef STQH
}

// ---------------------------------------------------------------------------
// K3: reduce 8 split partials + normalize + LePE + bias -> attnT [b][px][c].
// grid (49, 8) = 392 blocks, block 256.  (R9 kernel)
// ---------------------------------------------------------------------------
__global__ __launch_bounds__(256) void k_reduce(
    const __bf16* __restrict__ pO, const float* __restrict__ pl,
    const __bf16* __restrict__ vT,
    const float* __restrict__ lepe_w, const float* __restrict__ lepe_b,
    __bf16* __restrict__ attnT)
{
    __shared__ float wl[32][25];
    __shared__ float bl[32];
    const int tid = threadIdx.x;
    const int qt = blockIdx.x, bh = blockIdx.y;
    const int b = bh >> 2, h = bh & 3;
    const int c0h = h * HD;

    for (int i = tid; i < 800; i += 256) ((float*)wl)[i] = lepe_w[c0h * 25 + i];
    if (tid < 32) bl[tid] = lepe_b[c0h + tid];
    __syncthreads();

    const int q  = tid >> 2;                   // 0..63
    const int dg = (tid & 3) * 8;              // 0,8,16,24
    const size_t t = (size_t)bh * 49 + qt;

    float lt = 0.f;
    float o[8] = {0.f, 0.f, 0.f, 0.f, 0.f, 0.f, 0.f, 0.f};
    #pragma unroll
    for (int s = 0; s < NSPLIT; ++s) {
        lt += pl[(t * NSPLIT + s) * 64 + q];
        const bf16x8 pv = *(const bf16x8*)(pO + ((t * NSPLIT + s) * 64 + q) * 32 + dg);
        #pragma unroll
        for (int i = 0; i < 8; ++i) o[i] += (float)pv[i];
    }
    const float linv = 1.0f / lt;
    #pragma unroll
    for (int i = 0; i < 8; ++i) o[i] = o[i] * linv + bl[dg + i];

    const int px = qt * 64 + q;
    const int py = px / WIMG, pxx = px % WIMG;
    const __bf16* vtb = vT + ((size_t)b * NPIX) * CCH + c0h + dg;
    #pragma unroll
    for (int dy = 0; dy < 5; ++dy) {
        const int yy = py + dy - 2;
        if (yy < 0 || yy >= WIMG) continue;
        #pragma unroll
        for (int dx = 0; dx < 5; ++dx) {
            const int xx = pxx + dx - 2;
            if (xx < 0 || xx >= WIMG) continue;
            const bf16x8 vv = *(const bf16x8*)(vtb + (size_t)(yy * WIMG + xx) * CCH);
            const int tap = dy * 5 + dx;
            #pragma unroll
            for (int i = 0; i < 8; ++i) o[i] += (float)vv[i] * wl[dg + i][tap];
        }
    }
    bf16x8 ov = {(__bf16)o[0], (__bf16)o[1], (__bf16)o[2], (__bf16)o[3],
                 (__bf16)o[4], (__bf16)o[5], (__bf16)o[6], (__bf16)o[7]};
    *(bf16x8*)(attnT + ((size_t)(b * NPIX + px)) * CCH + c0h + dg) = ov;
}

// ---------------------------------------------------------------------------
// K4: out = proj_w @ (attn+lepe) + proj_b, bf16 MFMA, zero LDS.  (R9 kernel)
// grid (98, 4, 2) = 784 blocks, block 256; wave tile = 16 outputs x 16 px.
// ---------------------------------------------------------------------------
__global__ __launch_bounds__(256) void k_proj(
    const __bf16* __restrict__ attnT, const float* __restrict__ proj_w,
    const float* __restrict__ proj_b, float* __restrict__ out)
{
    const int tid = threadIdx.x;
    const int w = tid >> 6, lane = tid & 63;
    const int col = lane & 15, g = lane >> 4;
    const int px0 = blockIdx.x * 32 + (w >> 1) * 16;
    const int obase = blockIdx.y * 32 + (w & 1) * 16;
    const int b = blockIdx.z;

    const float* wrow = proj_w + (size_t)(obase + col) * CCH;
    const __bf16* abase = attnT + (size_t)(b * NPIX + px0) * CCH;

    f32x4 acc = {0.f, 0.f, 0.f, 0.f};
    #pragma unroll
    for (int ks = 0; ks < 4; ++ks) {
        const int c0 = ks * 32 + g * 8;
        const float4 wA = *(const float4*)(wrow + c0);
        const float4 wB = *(const float4*)(wrow + c0 + 4);
        bf16x8 af = {(__bf16)wA.x, (__bf16)wA.y, (__bf16)wA.z, (__bf16)wA.w,
                     (__bf16)wB.x, (__bf16)wB.y, (__bf16)wB.z, (__bf16)wB.w};
        const bf16x8 bf_ = *(const bf16x8*)(abase + (size_t)col * CCH + c0);
        acc = __builtin_amdgcn_mfma_f32_16x16x32_bf16(af, bf_, acc, 0, 0, 0);
    }

    const f32x4 pb = *(const f32x4*)(proj_b + obase + g * 4);
    #pragma unroll
    for (int r = 0; r < 4; ++r)
        out[(size_t)(b * CCH + obase + g * 4 + r) * NPIX + px0 + col] = acc[r] + pb[r];
}

// ---------------------------------------------------------------------------
extern "C" void kernel_launch(void* const* d_in, const int* in_sizes, int n_in,
                              void* d_out, int out_size, void* d_ws, size_t ws_size,
                              hipStream_t stream)
{
    const float* x      = (const float*)d_in[0];
    const float* qkv_w  = (const float*)d_in[1];
    const float* qkv_b  = (const float*)d_in[2];
    const float* lepe_w = (const float*)d_in[3];
    const float* lepe_b = (const float*)d_in[4];
    const float* proj_w = (const float*)d_in[5];
    const float* proj_b = (const float*)d_in[6];
    float* out = (float*)d_out;

    char* p = (char*)d_ws;                                   // ~22 MB total
    __bf16* qT    = (__bf16*)p;  p += (size_t)2 * NH * NPIX * HD * 2;       // 1.6 MB
    __bf16* kT    = (__bf16*)p;  p += (size_t)2 * NH * NPIX * HD * 2;       // 1.6 MB
    __bf16* vT    = (__bf16*)p;  p += (size_t)2 * NPIX * CCH * 2;           // 1.6 MB
    __bf16* vP    = (__bf16*)p;  p += (size_t)2 * CCH * NPIX * 2;           // 1.6 MB
    __bf16* attnT = (__bf16*)p;  p += (size_t)2 * NPIX * CCH * 2;           // 1.6 MB
    __bf16* pO    = (__bf16*)p;  p += (size_t)392 * NSPLIT * 64 * 32 * 2;   // 12.8 MB
    float*  pl    = (float*)p;                                              // 0.8 MB

    k_qkv   <<<dim3(49, 3, 2), dim3(256), 0, stream>>>(x, qkv_w, qkv_b, qT, kT, vT, vP);
    k_attn  <<<dim3(13, 8, 8), dim3(256), 0, stream>>>(qT, kT, vP, pO, pl);
    k_reduce<<<dim3(49, 8),    dim3(256), 0, stream>>>(pO, pl, vT, lepe_w, lepe_b, attnT);
    k_proj  <<<dim3(98, 4, 2), dim3(256), 0, stream>>>(attnT, proj_w, proj_b, out);
}